// Round 11
// baseline (431.314 us; speedup 1.0000x reference)
//
#include <hip/hip_runtime.h>
#include <hip/hip_bf16.h>
#include <stdint.h>

typedef __bf16 bf16x8 __attribute__((ext_vector_type(8)));
typedef float  f32x4  __attribute__((ext_vector_type(4)));

#define NROWS   8192
#define DIMK    128
#define NGROUPS 2048
#define RECON_N 6422528
#define SIM_BLOCKS   1024            // 64 row-tiles x 16 col-chunks(512)
#define RECON_BLOCKS 1568            // x256 thr x4 float4
#define GROUP_BLOCKS 512
#define MEGA_BLOCKS  3104            // 512*6 interleaved + 32 recon tail
#define PREP_BLOCKS  1032            // 1024 convert + 8 zero-S

// workspace layout (float offsets)
#define WS_S      0                  // S[8192], atomic accum (zeroed by prep)
#define WS_G      8192
#define WS_E      16384
#define WS_RPART  24576              // 1568
#define WS_DPART  26144              // 512
#define WS_DONE   26656              // int counter (zeroed by prep)
#define WS_PB     26672              // byte 106688 (16B aligned); bf16 P, 2MB

__device__ __forceinline__ void async16(const void* g, void* l) {
    __builtin_amdgcn_global_load_lds(
        (const __attribute__((address_space(1))) void*)g,
        (__attribute__((address_space(3))) void*)l, 16, 0, 0);
}

__device__ __forceinline__ unsigned short f2bf(float f) {
    union { __hip_bfloat16 h; unsigned short u; } v;
    v.h = __float2bfloat16(f);
    return v.u;
}

// -------- k1: prep = convert P fp32->bf16, zero S and done-counter --------
__global__ __launch_bounds__(256) void prep_kernel(const float4* __restrict__ Pf,
                                                   uint2* __restrict__ Pb,
                                                   float* __restrict__ ws) {
    int bx = blockIdx.x;
    if (bx < 1024) {
        int idx = bx * 256 + threadIdx.x;        // 262144 float4s
        float4 a = Pf[idx];
        uint2 r;
        r.x = (uint32_t)f2bf(a.x) | ((uint32_t)f2bf(a.y) << 16);
        r.y = (uint32_t)f2bf(a.z) | ((uint32_t)f2bf(a.w) << 16);
        Pb[idx] = r;
    } else {
        int zb = bx - 1024;                      // 8 blocks zero S (2048 float4)
        ((float4*)(ws + WS_S))[zb * 256 + threadIdx.x] = (float4){0.f, 0.f, 0.f, 0.f};
        if (zb == 0 && threadIdx.x == 0)
            *(int*)(ws + WS_DONE) = 0;
    }
}

// -------- k2: mega = sim + recon + group, fan-in finalize --------
// supergroups of 6: r6 0,3 -> sim; 1,2,4 -> recon; 5 -> group. tail 32 -> recon.
__global__ __launch_bounds__(256, 3) void mega_kernel(
        const unsigned short* __restrict__ Pb,
        const float* __restrict__ Pf,
        const float4* __restrict__ X,
        const float4* __restrict__ Y,
        float* __restrict__ ws,
        float* __restrict__ out) {
    __shared__ unsigned short tile[128 * 128];   // 32 KB (B staging, sim only)
    __shared__ int isLast;
    const int bx = blockIdx.x;
    const int wave = threadIdx.x >> 6, lane = threadIdx.x & 63;

    int role, idx;                               // 0=sim 1=recon 2=group
    if (bx < 3072) {
        int r6 = bx % 6, c6 = bx / 6;
        if (r6 == 0)      { role = 0; idx = c6 * 2; }
        else if (r6 == 3) { role = 0; idx = c6 * 2 + 1; }
        else if (r6 == 5) { role = 2; idx = c6; }
        else              { role = 1; idx = c6 * 3 + (r6 == 1 ? 0 : (r6 == 2 ? 1 : 2)); }
    } else {
        role = 1; idx = 1536 + (bx - 3072);
    }

    if (role == 0) {
        // ---- sim: S[row] += sum_{j in 512-col chunk} exp(P_row . P_j * 10) ----
        float* S = ws + WS_S;
        const int wr = wave >> 1, wc = wave & 1;
        const int rowBase = (idx >> 4) * 128;
        const int colBase = (idx & 15) * 512;
        const int m = lane & 15, kq = lane >> 4;

        // A fragments straight from global (L2-hot): A[m][k], k = kq*8 (+kk*32)
        bf16x8 Af[4][4];
#pragma unroll
        for (int i = 0; i < 4; ++i) {
            const unsigned short* rowp =
                Pb + (size_t)(rowBase + wr * 64 + i * 16 + m) * DIMK + kq * 8;
#pragma unroll
            for (int kk = 0; kk < 4; ++kk)
                Af[i][kk] = *(const bf16x8*)(rowp + kk * 32);
        }

        // per-lane swizzled source offsets for B staging (round-10 verified):
        // logical 16B chunk (r,q) stored at phys (r,(q+r)&15)
        int srcOff[8];
#pragma unroll
        for (int i = 0; i < 8; ++i) {
            int chunk = (i * 4 + wave) * 64 + lane;
            int r = chunk >> 4, qp = chunk & 15;
            srcOff[i] = r * 256 + (((qp - r) & 15) << 4);
        }

        float rowAcc[4][4];
#pragma unroll
        for (int i = 0; i < 4; ++i)
#pragma unroll
            for (int r = 0; r < 4; ++r) rowAcc[i][r] = 0.f;

        for (int t = 0; t < 4; ++t) {
            {
                const char* g = (const char*)(Pb + (size_t)(colBase + t * 128) * DIMK);
#pragma unroll
                for (int i = 0; i < 8; ++i) {
                    int seg = i * 4 + wave;
                    async16(g + srcOff[i], (char*)tile + seg * 1024 + lane * 16);
                }
            }
            __syncthreads();

            // j-outer: only acc[4] live (16 regs) -> no spill
#pragma unroll
            for (int j = 0; j < 4; ++j) {
                int rl = wc * 64 + j * 16 + m;
                bf16x8 Bf[4];
#pragma unroll
                for (int kk = 0; kk < 4; ++kk)
                    Bf[kk] = *(const bf16x8*)((const char*)tile + rl * 256 +
                                              (((kq + kk * 4 + rl) & 15) << 4));
                f32x4 acc[4];
#pragma unroll
                for (int i = 0; i < 4; ++i) acc[i] = (f32x4){0.f, 0.f, 0.f, 0.f};
#pragma unroll
                for (int kk = 0; kk < 4; ++kk)
#pragma unroll
                    for (int i = 0; i < 4; ++i)
                        acc[i] = __builtin_amdgcn_mfma_f32_16x16x32_bf16(
                            Af[i][kk], Bf[kk], acc[i], 0, 0, 0);
#pragma unroll
                for (int i = 0; i < 4; ++i)
#pragma unroll
                    for (int r = 0; r < 4; ++r)
                        rowAcc[i][r] += __expf(acc[i][r] * 10.0f);
            }
            __syncthreads();
        }

        // reduce 16 lanes sharing a row, then one atomic per (row, col-group)
#pragma unroll
        for (int i = 0; i < 4; ++i)
#pragma unroll
            for (int r = 0; r < 4; ++r) {
                float sv = rowAcc[i][r];
                sv += __shfl_xor(sv, 1, 64);
                sv += __shfl_xor(sv, 2, 64);
                sv += __shfl_xor(sv, 4, 64);
                sv += __shfl_xor(sv, 8, 64);
                rowAcc[i][r] = sv;
            }
        if ((lane & 15) == 0) {
            int c = lane >> 4;
#pragma unroll
            for (int i = 0; i < 4; ++i)
#pragma unroll
                for (int r = 0; r < 4; ++r)
                    atomicAdd(&S[rowBase + wr * 64 + i * 16 + c * 4 + r], rowAcc[i][r]);
        }
    } else if (role == 1) {
        // ---------------- recon ----------------
        __shared__ float red[4];
        int base = idx * 1024 + threadIdx.x;
        float4 a0 = X[base],       b0 = Y[base];
        float4 a1 = X[base + 256], b1 = Y[base + 256];
        float4 a2 = X[base + 512], b2 = Y[base + 512];
        float4 a3 = X[base + 768], b3 = Y[base + 768];
        float s = 0.f, d;
        d = a0.x - b0.x; s += d * d;  d = a0.y - b0.y; s += d * d;
        d = a0.z - b0.z; s += d * d;  d = a0.w - b0.w; s += d * d;
        d = a1.x - b1.x; s += d * d;  d = a1.y - b1.y; s += d * d;
        d = a1.z - b1.z; s += d * d;  d = a1.w - b1.w; s += d * d;
        d = a2.x - b2.x; s += d * d;  d = a2.y - b2.y; s += d * d;
        d = a2.z - b2.z; s += d * d;  d = a2.w - b2.w; s += d * d;
        d = a3.x - b3.x; s += d * d;  d = a3.y - b3.y; s += d * d;
        d = a3.z - b3.z; s += d * d;  d = a3.w - b3.w; s += d * d;
#pragma unroll
        for (int mm = 1; mm < 64; mm <<= 1) s += __shfl_xor(s, mm, 64);
        if (lane == 0) red[wave] = s;
        __syncthreads();
        if (threadIdx.x == 0)
            ws[WS_RPART + idx] = red[0] + red[1] + red[2] + red[3];
    } else {
        // ---------------- group ----------------
        __shared__ float dred[4];
        float* G = ws + WS_G;
        float* E = ws + WS_E;
        int g = idx * 4 + wave;
        const float* base = Pf + (size_t)g * 4 * DIMK;
        float v[4][2];
#pragma unroll
        for (int r = 0; r < 4; ++r) {
            v[r][0] = base[r * DIMK + lane];
            v[r][1] = base[r * DIMK + 64 + lane];
        }
        float dmat[4][4];
#pragma unroll
        for (int r = 0; r < 4; ++r)
#pragma unroll
            for (int s2 = r; s2 < 4; ++s2) {
                float p = v[r][0] * v[s2][0] + v[r][1] * v[s2][1];
#pragma unroll
                for (int mm = 1; mm < 64; mm <<= 1) p += __shfl_xor(p, mm, 64);
                dmat[r][s2] = p; dmat[s2][r] = p;
            }
        if (lane == 0) {
            float distp = 0.f;
#pragma unroll
            for (int r = 0; r < 4; ++r)
#pragma unroll
                for (int s2 = r + 1; s2 < 4; ++s2)
                    distp += dmat[r][r] + dmat[s2][s2] - 2.f * dmat[r][s2];
            dred[wave] = distp;
#pragma unroll
            for (int r = 0; r < 4; ++r) {
                float Gs = 0.f, Es = 0.f;
#pragma unroll
                for (int s2 = 0; s2 < 4; ++s2) {
                    float sim = dmat[r][s2] * 10.0f;
                    float e = __expf(sim);
                    Gs += e;
                    if (sim == 1.0f) Es += e;
                }
                G[g * 4 + r] = Gs;
                E[g * 4 + r] = Es;
            }
        }
        __syncthreads();
        if (threadIdx.x == 0)
            ws[WS_DPART + idx] = dred[0] + dred[1] + dred[2] + dred[3];
    }

    // ---------------- fan-in finalize ----------------
    __threadfence();                 // every thread: flush its stores device-wide
    __syncthreads();
    if (threadIdx.x == 0) {
        int old = atomicAdd((int*)(ws + WS_DONE), 1);
        isLast = (old == MEGA_BLOCKS - 1);
    }
    __syncthreads();
    if (isLast) {
        __threadfence();             // acquire
        __shared__ float redc[4], redr[4], redd[4];
        const float* S = ws + WS_S;
        const float* G = ws + WS_G;
        const float* E = ws + WS_E;
        float c = 0.f;
        for (int r = threadIdx.x; r < NROWS; r += 256)
            c += __logf(S[r] - E[r]) - __logf(G[r] - E[r]);
        float rs = 0.f;
        for (int i = threadIdx.x; i < RECON_BLOCKS; i += 256) rs += ws[WS_RPART + i];
        float ds = 0.f;
        for (int i = threadIdx.x; i < GROUP_BLOCKS; i += 256) ds += ws[WS_DPART + i];
#pragma unroll
        for (int mm = 1; mm < 64; mm <<= 1) {
            c  += __shfl_xor(c,  mm, 64);
            rs += __shfl_xor(rs, mm, 64);
            ds += __shfl_xor(ds, mm, 64);
        }
        if (lane == 0) { redc[wave] = c; redr[wave] = rs; redd[wave] = ds; }
        __syncthreads();
        if (threadIdx.x == 0) {
            float closs = (redc[0] + redc[1] + redc[2] + redc[3]) / (float)NROWS;
            float recon = (redr[0] + redr[1] + redr[2] + redr[3]) / (float)RECON_N;
            float dist  = (redd[0] + redd[1] + redd[2] + redd[3]) / (float)(NGROUPS * 6 * DIMK);
            out[0] = recon + closs + dist;
            out[1] = closs;
            out[2] = recon;
            out[3] = dist;
        }
    }
}

extern "C" void kernel_launch(void* const* d_in, const int* in_sizes, int n_in,
                              void* d_out, int out_size, void* d_ws, size_t ws_size,
                              hipStream_t stream) {
    const float* P  = (const float*)d_in[0];    // projections 8192x128 fp32
    const float4* X = (const float4*)d_in[1];   // xrecon 8192x784 fp32
    const float4* Y = (const float4*)d_in[2];   // recon_label fp32
    float* out = (float*)d_out;                 // 4 fp32 scalars
    float* w = (float*)d_ws;
    unsigned short* Pb = (unsigned short*)(w + WS_PB);

    prep_kernel<<<PREP_BLOCKS, 256, 0, stream>>>((const float4*)P, (uint2*)Pb, w);
    mega_kernel<<<MEGA_BLOCKS, 256, 0, stream>>>(Pb, P, X, Y, w, out);
}

// Round 12
// 126.155 us; speedup vs baseline: 3.4189x; 3.4189x over previous
//
#include <hip/hip_runtime.h>
#include <hip/hip_bf16.h>
#include <stdint.h>

typedef __bf16 bf16x8 __attribute__((ext_vector_type(8)));
typedef float  f32x4  __attribute__((ext_vector_type(4)));

#define NROWS   8192
#define DIMK    128
#define NGROUPS 2048
#define RECON_N 6422528
#define SIM_BLOCKS   1024            // 64 row-tiles x 16 col-chunks(512)
#define RECON_BLOCKS 1568            // x256 thr x4 float4
#define GROUP_BLOCKS 512
#define FUSED_BLOCKS 3104            // 512*6 + 32 recon tail

// workspace layout (float offsets)
#define WS_SP     0                  // Sp[16][8192] plain-store slabs
#define WS_G      131072
#define WS_E      139264
#define WS_RPART  147456             // 1568
#define WS_DPART  149024             // 512
#define WS_PB     149536             // byte 598144 (16B aligned); bf16 P, 2MB

__device__ __forceinline__ void async16(const void* g, void* l) {
    __builtin_amdgcn_global_load_lds(
        (const __attribute__((address_space(1))) void*)g,
        (__attribute__((address_space(3))) void*)l, 16, 0, 0);
}

__device__ __forceinline__ unsigned short f2bf(float f) {
    union { __hip_bfloat16 h; unsigned short u; } v;
    v.h = __float2bfloat16(f);
    return v.u;
}

// -------- k1: convert P fp32 -> bf16 --------
__global__ __launch_bounds__(256) void prep_kernel(const float4* __restrict__ Pf,
                                                   uint2* __restrict__ Pb) {
    int idx = blockIdx.x * 256 + threadIdx.x;    // 262144 float4s
    float4 a = Pf[idx];
    uint2 r;
    r.x = (uint32_t)f2bf(a.x) | ((uint32_t)f2bf(a.y) << 16);
    r.y = (uint32_t)f2bf(a.z) | ((uint32_t)f2bf(a.w) << 16);
    Pb[idx] = r;
}

// -------- k2: fused = sim + recon + group, role-interleaved, NO fences -------
// supergroups of 6: r6 0,3 -> sim; 1,2,4 -> recon; 5 -> group. tail 32 -> recon.
__global__ __launch_bounds__(256, 3) void fused_kernel(
        const unsigned short* __restrict__ Pb,
        const float* __restrict__ Pf,
        const float4* __restrict__ X,
        const float4* __restrict__ Y,
        float* __restrict__ ws) {
    __shared__ unsigned short tile[128 * 128];   // 32 KB (sim B staging)
    const int bx = blockIdx.x;
    const int wave = threadIdx.x >> 6, lane = threadIdx.x & 63;

    int role, idx;                               // 0=sim 1=recon 2=group
    if (bx < 3072) {
        int r6 = bx % 6, c6 = bx / 6;
        if (r6 == 0)      { role = 0; idx = c6 * 2; }
        else if (r6 == 3) { role = 0; idx = c6 * 2 + 1; }
        else if (r6 == 5) { role = 2; idx = c6; }
        else              { role = 1; idx = c6 * 3 + (r6 == 1 ? 0 : (r6 == 2 ? 1 : 2)); }
    } else {
        role = 1; idx = 1536 + (bx - 3072);
    }

    if (role == 0) {
        // ---- sim: Sp[chunk][row] = sum_{j in 512-col chunk} exp(P_row.P_j*10)
        __shared__ float sred[2][2][64];         // [wc][wr][row-in-64]
        float* Sp = ws + WS_SP;
        const int wr = wave >> 1, wc = wave & 1;
        const int rowBase = (idx >> 4) * 128;
        const int colBase = (idx & 15) * 512;
        const int m = lane & 15, kq = lane >> 4;

        // A fragments straight from global (L2-hot)
        bf16x8 Af[4][4];
#pragma unroll
        for (int i = 0; i < 4; ++i) {
            const unsigned short* rowp =
                Pb + (size_t)(rowBase + wr * 64 + i * 16 + m) * DIMK + kq * 8;
#pragma unroll
            for (int kk = 0; kk < 4; ++kk)
                Af[i][kk] = *(const bf16x8*)(rowp + kk * 32);
        }

        // swizzled staging source offsets: logical (r,q) -> phys (r,(q+r)&15)
        int srcOff[8];
#pragma unroll
        for (int i = 0; i < 8; ++i) {
            int chunk = (i * 4 + wave) * 64 + lane;
            int r = chunk >> 4, qp = chunk & 15;
            srcOff[i] = r * 256 + (((qp - r) & 15) << 4);
        }

        float rowAcc[4][4];
#pragma unroll
        for (int i = 0; i < 4; ++i)
#pragma unroll
            for (int r = 0; r < 4; ++r) rowAcc[i][r] = 0.f;

        for (int t = 0; t < 4; ++t) {
            {
                const char* g = (const char*)(Pb + (size_t)(colBase + t * 128) * DIMK);
#pragma unroll
                for (int i = 0; i < 8; ++i) {
                    int seg = i * 4 + wave;
                    async16(g + srcOff[i], (char*)tile + seg * 1024 + lane * 16);
                }
            }
            __syncthreads();

            // j-outer: only acc[4] live -> no spill
#pragma unroll
            for (int j = 0; j < 4; ++j) {
                int rl = wc * 64 + j * 16 + m;
                bf16x8 Bf[4];
#pragma unroll
                for (int kk = 0; kk < 4; ++kk)
                    Bf[kk] = *(const bf16x8*)((const char*)tile + rl * 256 +
                                              (((kq + kk * 4 + rl) & 15) << 4));
                f32x4 acc[4];
#pragma unroll
                for (int i = 0; i < 4; ++i) acc[i] = (f32x4){0.f, 0.f, 0.f, 0.f};
#pragma unroll
                for (int kk = 0; kk < 4; ++kk)
#pragma unroll
                    for (int i = 0; i < 4; ++i)
                        acc[i] = __builtin_amdgcn_mfma_f32_16x16x32_bf16(
                            Af[i][kk], Bf[kk], acc[i], 0, 0, 0);
#pragma unroll
                for (int i = 0; i < 4; ++i)
#pragma unroll
                    for (int r = 0; r < 4; ++r)
                        rowAcc[i][r] += __expf(acc[i][r] * 10.0f);
            }
            __syncthreads();
        }

        // 16-lane row reduce, combine col-halves via sred, one store per row
#pragma unroll
        for (int i = 0; i < 4; ++i)
#pragma unroll
            for (int r = 0; r < 4; ++r) {
                float sv = rowAcc[i][r];
                sv += __shfl_xor(sv, 1, 64);
                sv += __shfl_xor(sv, 2, 64);
                sv += __shfl_xor(sv, 4, 64);
                sv += __shfl_xor(sv, 8, 64);
                rowAcc[i][r] = sv;
            }
        if ((lane & 15) == 0) {
            int c = lane >> 4;
#pragma unroll
            for (int i = 0; i < 4; ++i)
#pragma unroll
                for (int r = 0; r < 4; ++r)
                    sred[wc][wr][i * 16 + c * 4 + r] = rowAcc[i][r];
        }
        __syncthreads();
        if (wc == 0) {
            float v = sred[0][wr][lane] + sred[1][wr][lane];
            Sp[(size_t)(idx & 15) * NROWS + rowBase + wr * 64 + lane] = v;
        }
    } else if (role == 1) {
        // ---------------- recon ----------------
        __shared__ float red[4];
        int base = idx * 1024 + threadIdx.x;
        float4 a0 = X[base],       b0 = Y[base];
        float4 a1 = X[base + 256], b1 = Y[base + 256];
        float4 a2 = X[base + 512], b2 = Y[base + 512];
        float4 a3 = X[base + 768], b3 = Y[base + 768];
        float s = 0.f, d;
        d = a0.x - b0.x; s += d * d;  d = a0.y - b0.y; s += d * d;
        d = a0.z - b0.z; s += d * d;  d = a0.w - b0.w; s += d * d;
        d = a1.x - b1.x; s += d * d;  d = a1.y - b1.y; s += d * d;
        d = a1.z - b1.z; s += d * d;  d = a1.w - b1.w; s += d * d;
        d = a2.x - b2.x; s += d * d;  d = a2.y - b2.y; s += d * d;
        d = a2.z - b2.z; s += d * d;  d = a2.w - b2.w; s += d * d;
        d = a3.x - b3.x; s += d * d;  d = a3.y - b3.y; s += d * d;
        d = a3.z - b3.z; s += d * d;  d = a3.w - b3.w; s += d * d;
#pragma unroll
        for (int mm = 1; mm < 64; mm <<= 1) s += __shfl_xor(s, mm, 64);
        if (lane == 0) red[wave] = s;
        __syncthreads();
        if (threadIdx.x == 0)
            ws[WS_RPART + idx] = red[0] + red[1] + red[2] + red[3];
    } else {
        // ---------------- group ----------------
        __shared__ float dred[4];
        float* G = ws + WS_G;
        float* E = ws + WS_E;
        int g = idx * 4 + wave;
        const float* base = Pf + (size_t)g * 4 * DIMK;
        float v[4][2];
#pragma unroll
        for (int r = 0; r < 4; ++r) {
            v[r][0] = base[r * DIMK + lane];
            v[r][1] = base[r * DIMK + 64 + lane];
        }
        float dmat[4][4];
#pragma unroll
        for (int r = 0; r < 4; ++r)
#pragma unroll
            for (int s2 = r; s2 < 4; ++s2) {
                float p = v[r][0] * v[s2][0] + v[r][1] * v[s2][1];
#pragma unroll
                for (int mm = 1; mm < 64; mm <<= 1) p += __shfl_xor(p, mm, 64);
                dmat[r][s2] = p; dmat[s2][r] = p;
            }
        if (lane == 0) {
            float distp = 0.f;
#pragma unroll
            for (int r = 0; r < 4; ++r)
#pragma unroll
                for (int s2 = r + 1; s2 < 4; ++s2)
                    distp += dmat[r][r] + dmat[s2][s2] - 2.f * dmat[r][s2];
            dred[wave] = distp;
#pragma unroll
            for (int r = 0; r < 4; ++r) {
                float Gs = 0.f, Es = 0.f;
#pragma unroll
                for (int s2 = 0; s2 < 4; ++s2) {
                    float sim = dmat[r][s2] * 10.0f;
                    float e = __expf(sim);
                    Gs += e;
                    if (sim == 1.0f) Es += e;
                }
                G[g * 4 + r] = Gs;
                E[g * 4 + r] = Es;
            }
        }
        __syncthreads();
        if (threadIdx.x == 0)
            ws[WS_DPART + idx] = dred[0] + dred[1] + dred[2] + dred[3];
    }
}

// -------- k3: finalize — one 1024-thread block --------
__global__ __launch_bounds__(1024) void finalize_kernel(const float* __restrict__ ws,
                                                        float* __restrict__ out) {
    __shared__ float redc[16], redr[16], redd[16];
    const float* Sp = ws + WS_SP;
    const float* G  = ws + WS_G;
    const float* E  = ws + WS_E;

    float c = 0.f;
    for (int r = threadIdx.x; r < NROWS; r += 1024) {
        float Sv = 0.f;
#pragma unroll
        for (int q = 0; q < 16; ++q) Sv += Sp[q * NROWS + r];
        c += __logf(Sv - E[r]) - __logf(G[r] - E[r]);
    }
    float rs = 0.f;
    for (int i = threadIdx.x; i < RECON_BLOCKS; i += 1024) rs += ws[WS_RPART + i];
    float ds = 0.f;
    for (int i = threadIdx.x; i < GROUP_BLOCKS; i += 1024) ds += ws[WS_DPART + i];

#pragma unroll
    for (int mm = 1; mm < 64; mm <<= 1) {
        c  += __shfl_xor(c,  mm, 64);
        rs += __shfl_xor(rs, mm, 64);
        ds += __shfl_xor(ds, mm, 64);
    }
    int wave = threadIdx.x >> 6, lane = threadIdx.x & 63;
    if (lane == 0) { redc[wave] = c; redr[wave] = rs; redd[wave] = ds; }
    __syncthreads();
    if (threadIdx.x == 0) {
        float cs = 0.f, rss = 0.f, dss = 0.f;
#pragma unroll
        for (int i = 0; i < 16; ++i) { cs += redc[i]; rss += redr[i]; dss += redd[i]; }
        float closs = cs / (float)NROWS;
        float recon = rss / (float)RECON_N;
        float dist  = dss / (float)(NGROUPS * 6 * DIMK);
        out[0] = recon + closs + dist;
        out[1] = closs;
        out[2] = recon;
        out[3] = dist;
    }
}

extern "C" void kernel_launch(void* const* d_in, const int* in_sizes, int n_in,
                              void* d_out, int out_size, void* d_ws, size_t ws_size,
                              hipStream_t stream) {
    const float* P  = (const float*)d_in[0];    // projections 8192x128 fp32
    const float4* X = (const float4*)d_in[1];   // xrecon 8192x784 fp32
    const float4* Y = (const float4*)d_in[2];   // recon_label fp32
    float* out = (float*)d_out;                 // 4 fp32 scalars
    float* w = (float*)d_ws;
    unsigned short* Pb = (unsigned short*)(w + WS_PB);

    prep_kernel<<<1024, 256, 0, stream>>>((const float4*)P, (uint2*)Pb);
    fused_kernel<<<FUSED_BLOCKS, 256, 0, stream>>>(Pb, P, X, Y, w);
    finalize_kernel<<<1, 1024, 0, stream>>>(w, out);
}